// Round 5
// baseline (328.761 us; speedup 1.0000x reference)
//
#include <hip/hip_runtime.h>
#include <math.h>

// out = relu( tile(pool2(x1),2) + tile(pool4(x2),4) + tile(pool8(x3),8)
//             + tile(pool16(x4),16) + ff )   all NCHW fp32, B=16, out 16x256x24x24.
//
// Round-5: single dispatch, zero ws. vs round-4 (124us, VGPR=32, latency-bound
// with ~1 load in flight/wave): block = 384 threads so each thread does
// EXACTLY ONE task from each pool phase in STRAIGHT-LINE code (no branches in
// the pool section) -> compiler can batch the independent global_load_dwordx4.
// Phase task counts per block: A(K=2)=384, B(K=4)=384, C(K=8)=384, D(K=16)=384.
// Grid = (b=16, oh=24, col-quarter=4) = 1536 blocks.

namespace {

__device__ __forceinline__ float fmax4(const float4 v) {
  return fmaxf(fmaxf(v.x, v.y), fmaxf(v.z, v.w));
}
__device__ __forceinline__ float4 ld4(const float* p) {
  return *reinterpret_cast<const float4*>(p);
}

__global__ __launch_bounds__(384, 4) void fused_block(const float* __restrict__ x1,
                                                      const float* __restrict__ x2,
                                                      const float* __restrict__ x3,
                                                      const float* __restrict__ x4,
                                                      const float* __restrict__ ff,
                                                      float* __restrict__ out) {
  __shared__ __attribute__((aligned(16))) float s1[128 * 6];
  __shared__ __attribute__((aligned(16))) float s2[64 * 6];
  __shared__ __attribute__((aligned(16))) float s3[32 * 6];
  __shared__ __attribute__((aligned(16))) float s4[16 * 6];

  const int blk = blockIdx.x;      // 0..1535
  const int b   = blk / 96;
  const int rem = blk % 96;
  const int oh  = rem >> 2;        // 0..23
  const int q4  = rem & 3;         // output cols q4*6 .. q4*6+5
  const int tid = threadIdx.x;     // 0..383

  // ---- Addresses for all four phases (no control flow below) ----
  // A: x1 [16,128,48,48], K=2. task = ch(128) x pid(3); one float4 = 2 windows.
  const int chA = tid / 3, pid = tid - chA * 3;
  const float* pA = x1 + (size_t)(b * 128 + chA) * 2304 + oh * 96 + q4 * 12 + pid * 4;
  // B: x2 [16,64,96,96], K=4. task = ch(64) x ow(6).
  const int chB = tid / 6, owB = tid - chB * 6;
  const float* pB = x2 + (size_t)(b * 64 + chB) * 9216 + oh * 384 + (q4 * 6 + owB) * 4;
  // C: x3 [16,32,192,192], K=8. task = ch(32) x ow(6) x hf(2); 2 lanes/window.
  const int chC = tid / 12, rC = tid - chC * 12, owC = rC >> 1, hf = rC & 1;
  const float* pC = x3 + (size_t)(b * 32 + chC) * 36864 + oh * 1536 + (q4 * 6 + owC) * 8 + hf * 4;
  // D: x4 [16,16,384,384], K=16. task = ch(16) x ow(6) x qq(4); 4 lanes/window.
  const int chD = tid / 24, rD = tid - chD * 24, owD = rD >> 2, qq = rD & 3;
  const float* pD = x4 + (size_t)(b * 16 + chD) * 147456 + oh * 6144 + (q4 * 6 + owD) * 16 + qq * 4;

  // ---- Issue all loads (independent; compiler batches) ----
  float4 va[2], vb[4], vc[8], vd[16];
#pragma unroll
  for (int r = 0; r < 16; ++r) vd[r] = ld4(pD + r * 384);
#pragma unroll
  for (int r = 0; r < 8; ++r) vc[r] = ld4(pC + r * 192);
#pragma unroll
  for (int r = 0; r < 4; ++r) vb[r] = ld4(pB + r * 96);
#pragma unroll
  for (int r = 0; r < 2; ++r) va[r] = ld4(pA + r * 48);

  // ---- Reductions + LDS writes ----
  // A: float2 (2 windows)
  {
    float2 r2;
    r2.x = fmaxf(fmaxf(va[0].x, va[0].y), fmaxf(va[1].x, va[1].y));
    r2.y = fmaxf(fmaxf(va[0].z, va[0].w), fmaxf(va[1].z, va[1].w));
    *reinterpret_cast<float2*>(&s1[chA * 6 + pid * 2]) = r2;
  }
  // B
  {
    float m = fmaxf(fmaxf(fmax4(vb[0]), fmax4(vb[1])), fmaxf(fmax4(vb[2]), fmax4(vb[3])));
    s2[chB * 6 + owB] = m;
  }
  // C: pairwise tree then shfl
  {
    float m0 = fmaxf(fmax4(vc[0]), fmax4(vc[1]));
    float m1 = fmaxf(fmax4(vc[2]), fmax4(vc[3]));
    float m2 = fmaxf(fmax4(vc[4]), fmax4(vc[5]));
    float m3 = fmaxf(fmax4(vc[6]), fmax4(vc[7]));
    float m  = fmaxf(fmaxf(m0, m1), fmaxf(m2, m3));
    m = fmaxf(m, __shfl_xor(m, 1));
    if (hf == 0) s3[chC * 6 + owC] = m;
  }
  // D
  {
    float m0 = fmaxf(fmaxf(fmax4(vd[0]),  fmax4(vd[1])),  fmaxf(fmax4(vd[2]),  fmax4(vd[3])));
    float m1 = fmaxf(fmaxf(fmax4(vd[4]),  fmax4(vd[5])),  fmaxf(fmax4(vd[6]),  fmax4(vd[7])));
    float m2 = fmaxf(fmaxf(fmax4(vd[8]),  fmax4(vd[9])),  fmaxf(fmax4(vd[10]), fmax4(vd[11])));
    float m3 = fmaxf(fmaxf(fmax4(vd[12]), fmax4(vd[13])), fmaxf(fmax4(vd[14]), fmax4(vd[15])));
    float m  = fmaxf(fmaxf(m0, m1), fmaxf(m2, m3));
    m = fmaxf(m, __shfl_xor(m, 1));
    m = fmaxf(m, __shfl_xor(m, 2));
    if (qq == 0) s4[chD * 6 + owD] = m;
  }

  __syncthreads();

  // ---- Combine: 768 float2-tasks = 2 iters x 384 threads ----
#pragma unroll
  for (int it = 0; it < 2; ++it) {
    const int e = it * 384 + tid;
    const int c = e / 3, cp = e - c * 3;
    const float2 a1 = *reinterpret_cast<const float2*>(&s1[(c & 127) * 6 + cp * 2]);
    const float2 a2 = *reinterpret_cast<const float2*>(&s2[(c & 63)  * 6 + cp * 2]);
    const float2 a3 = *reinterpret_cast<const float2*>(&s3[(c & 31)  * 6 + cp * 2]);
    const float2 a4 = *reinterpret_cast<const float2*>(&s4[(c & 15)  * 6 + cp * 2]);
    const size_t o = (size_t)(b * 256 + c) * 576 + oh * 24 + q4 * 6 + cp * 2;
    const float2 f = *reinterpret_cast<const float2*>(ff + o);
    float2 r;
    r.x = fmaxf((((a1.x + a2.x) + a3.x) + a4.x) + f.x, 0.0f);
    r.y = fmaxf((((a1.y + a2.y) + a3.y) + a4.y) + f.y, 0.0f);
    *reinterpret_cast<float2*>(out + o) = r;
  }
}

}  // namespace

extern "C" void kernel_launch(void* const* d_in, const int* in_sizes, int n_in,
                              void* d_out, int out_size, void* d_ws, size_t ws_size,
                              hipStream_t stream) {
  const float* x1 = (const float*)d_in[0];  // [16,128,48,48]
  const float* x2 = (const float*)d_in[1];  // [16,64,96,96]
  const float* x3 = (const float*)d_in[2];  // [16,32,192,192]
  const float* x4 = (const float*)d_in[3];  // [16,16,384,384]
  const float* ff = (const float*)d_in[4];  // [16,256,24,24]
  float* out = (float*)d_out;               // [16,256,24,24]
  (void)d_ws; (void)ws_size; (void)in_sizes; (void)n_in; (void)out_size;

  fused_block<<<1536, 384, 0, stream>>>(x1, x2, x3, x4, ff, out);
}